// Round 10
// baseline (491.907 us; speedup 1.0000x reference)
//
#include <hip/hip_runtime.h>

#define NUM_INST 64
#define BLOCK 256
#define NWAVES 4
#define GRID 2048
#define BUFF 576   // per-wave staging buffer: 512 data floats + 64 labels (floats-equiv)

typedef float f32x4 __attribute__((ext_vector_type(4)));
typedef short s16x8 __attribute__((ext_vector_type(8)));
typedef int   i32x4 __attribute__((ext_vector_type(4)));

union FragU { i32x4 i; s16x8 s; };

typedef __attribute__((address_space(1))) const unsigned GU;
typedef __attribute__((address_space(3))) unsigned LU;

// direct global->LDS DMA (compiler never auto-emits): dst is wave-uniform base,
// HW writes base + lane*size; src is per-lane. Our staging layout is exactly linear.
__device__ __forceinline__ void gload16(const void* g, void* l) {
    __builtin_amdgcn_global_load_lds((GU*)g, (LU*)l, 16, 0, 0);
}
__device__ __forceinline__ void gload4(const void* g, void* l) {
    __builtin_amdgcn_global_load_lds((GU*)g, (LU*)l, 4, 0, 0);
}

// pack {bf16_rne(v), bf16_rne(v - bf16(v))} into one u32 (hi = low16/even k-slot).
// RNE keeps split error unbiased; fp32 MFMA accumulation -> sums exact to ~2^-24 rel.
__device__ __forceinline__ unsigned hilo_pack(float v) {
    unsigned h, p;
    asm("v_cvt_pk_bf16_f32 %0, %1, %1" : "=v"(h) : "v"(v));
    const float r = v - __uint_as_float(h << 16);
    asm("v_cvt_pk_bf16_f32 %0, %1, %2" : "=v"(p) : "v"(v), "v"(r));
    return p;
}

// one 16-row chunk: B1 = [v | ones | 0], B2 = [v^2 | 0]; A = one-hot(label) per 16-label
// tile, 1.0 in BOTH 16-bit halves (pairs hi+lo k-slots). lbl==-1 annihilates junk rows.
__device__ __forceinline__ void chunk_mfma(const int* lbl, float v0, float v1,
                                           float v2, float v3, int c,
                                           f32x4* accS, f32x4* accQ) {
    FragU B1, B2;
    if (c < 8) {
        B1.i = (i32x4){(int)hilo_pack(v0), (int)hilo_pack(v1),
                       (int)hilo_pack(v2), (int)hilo_pack(v3)};
        B2.i = (i32x4){(int)hilo_pack(v0 * v0), (int)hilo_pack(v1 * v1),
                       (int)hilo_pack(v2 * v2), (int)hilo_pack(v3 * v3)};
    } else {
        const int one = (c == 8) ? 0x3F80 : 0;  // count column: 1.0 in hi slot only
        B1.i = (i32x4){one, one, one, one};
        B2.i = (i32x4){0, 0, 0, 0};
    }
#pragma unroll
    for (int t = 0; t < 4; ++t) {
        const int m = c + 16 * t;
        FragU A;
        A.i = (i32x4){ lbl[0] == m ? (int)0x3F803F80 : 0,
                       lbl[1] == m ? (int)0x3F803F80 : 0,
                       lbl[2] == m ? (int)0x3F803F80 : 0,
                       lbl[3] == m ? (int)0x3F803F80 : 0 };
        accS[t] = __builtin_amdgcn_mfma_f32_16x16x32_bf16(A.s, B1.s, accS[t], 0, 0, 0);
        accQ[t] = __builtin_amdgcn_mfma_f32_16x16x32_bf16(A.s, B2.s, accQ[t], 0, 0, 0);
    }
}

__global__ __launch_bounds__(BLOCK, 8) void vsl_main(const float* __restrict__ rows,
                                                     const int* __restrict__ labels,
                                                     float* __restrict__ gacc, int n) {
    // per-wave double-buffered staging; epilogue red aliases sm (after syncthreads)
    __shared__ __align__(16) float sm[NWAVES * 2 * BUFF];  // 18432 B
    const int tid = threadIdx.x;
    const int w = tid >> 6;
    const int lane = tid & 63;
    const int g = lane >> 4;   // k-group 0..3
    const int c = lane & 15;   // B col (stat) / A row (label within 16-tile)
    const int cc = c & 7;

    float* const buf0 = sm + w * (2 * BUFF);
    float* const buf1 = buf0 + BUFF;

    f32x4 accS[4], accQ[4];
#pragma unroll
    for (int t = 0; t < 4; ++t) { accS[t] = (f32x4){0,0,0,0}; accQ[t] = (f32x4){0,0,0,0}; }

    const int waveId = blockIdx.x * NWAVES + w;
    const int step = GRID * NWAVES;
    const int nSC = (n + 63) >> 6;   // super-chunks of 64 rows (4 MFMA chunks)
    const int nFullSC = n >> 6;      // fully in-bounds -> staged fast path

    int sc = waveId;
    bool stCur = (sc < nFullSC);
    if (stCur) {
        const float* src = rows + (size_t)sc * 512;
        gload16(src + (size_t)lane * 4, buf0);               // 1 KB: rows 0-31
        gload16(src + 256 + (size_t)lane * 4, buf0 + 256);   // 1 KB: rows 32-63
        gload4(labels + (size_t)sc * 64 + lane, buf0 + 512); // 256 B labels
    }
    bool flip = false;

    for (; sc < nSC; sc += step) {
        const int scn = sc + step;
        const bool stNext = (scn < nFullSC);
        float* const cur = flip ? buf1 : buf0;
        float* const nxt = flip ? buf0 : buf1;

        if (stCur) {
            if (stNext) {
                const float* src = rows + (size_t)scn * 512;
                gload16(src + (size_t)lane * 4, nxt);
                gload16(src + 256 + (size_t)lane * 4, nxt + 256);
                gload4(labels + (size_t)scn * 64 + lane, nxt + 512);
                // counted wait (T4): cur's 3 loads done, nxt's 3 stay in flight
                asm volatile("s_waitcnt vmcnt(3)" ::: "memory");
            } else {
                asm volatile("s_waitcnt vmcnt(0)" ::: "memory");
            }
#pragma unroll
            for (int ck = 0; ck < 4; ++ck) {
                const float* rc = cur + ck * 128;
                const int* lc = (const int*)(cur + 512) + ck * 16;
                const int2 lp = *(const int2*)(lc + 2 * g);      // labels r0, r0+1
                const int2 lq = *(const int2*)(lc + 2 * g + 8);  // labels r0+8, r0+9
                const int lbl[4] = {lp.x, lp.y, lq.x, lq.y};
                const float v0 = rc[g * 16 + cc];        // row 2g    (ds_read2-mergeable)
                const float v1 = rc[g * 16 + 8 + cc];    // row 2g+1
                const float v2 = rc[g * 16 + 64 + cc];   // row 2g+8
                const float v3 = rc[g * 16 + 72 + cc];   // row 2g+9
                chunk_mfma(lbl, v0, v1, v2, v3, c, accS, accQ);
            }
        } else {
            // partial super-chunk (at most one per wave): clamped direct-global path
            const int base = sc << 6;
#pragma unroll
            for (int ck = 0; ck < 4; ++ck) {
                const int r0 = base + ck * 16 + 2 * g;
                int lbl[4];
                float v[4];
#pragma unroll
                for (int q = 0; q < 4; ++q) {
                    const int rq = r0 + (q & 1) + ((q >> 1) << 3);
                    const bool ok = rq < n;
                    const int rs = ok ? rq : 0;
                    v[q] = rows[(size_t)rs * 8 + cc];
                    lbl[q] = ok ? labels[rs] : -1;  // -1 never matches -> row annihilated
                }
                chunk_mfma(lbl, v[0], v[1], v[2], v[3], c, accS, accQ);
            }
        }
        flip = !flip;
        stCur = stNext;
    }

    // ---- epilogue: C/D layout col=lane&15, row=(lane>>4)*4+reg (m89-verified) ----
    __syncthreads();        // all waves done looping; red aliases the staging memory
    float* const red = sm;  // [NWAVES*64][12]
#pragma unroll
    for (int t = 0; t < 4; ++t) {
#pragma unroll
        for (int rg = 0; rg < 4; ++rg) {
            const int Lr = 16 * t + 4 * g + rg;
            const float vS = accS[t][rg];
            if (c < 10) red[(w * 64 + Lr) * 12 + ((c < 8) ? c : (c == 8 ? 9 : 11))] = vS;
            float sq = accQ[t][rg];  // fold the 8 dim-columns -> ssq
            sq += __shfl_xor(sq, 1, 64);
            sq += __shfl_xor(sq, 2, 64);
            sq += __shfl_xor(sq, 4, 64);
            if (c == 0) red[(w * 64 + Lr) * 12 + 8] = sq;
        }
    }
    __syncthreads();

    for (int j = tid; j < NUM_INST * 10; j += BLOCK) {
        const int Lb = j / 10;
        const int st = j - Lb * 10;
        float v = 0;
#pragma unroll
        for (int ww = 0; ww < NWAVES; ++ww) v += red[(ww * 64 + Lb) * 12 + st];
        atomicAdd(&gacc[j], v);
    }
}

__global__ __launch_bounds__(64) void vsl_final(const float* __restrict__ gacc,
                                                float* __restrict__ out) {
    const int s = threadIdx.x;  // one thread per instance, 1 wave
    float val = 0.0f;
    const float* base = &gacc[s * 10];
    const float cnt = base[9];
    if (s != 0 && cnt > 0.0f) {
        const float ss = base[8];
        float m2 = 0.0f;
#pragma unroll
        for (int d = 0; d < 8; ++d) {
            const float sd = base[d];
            m2 += sd * sd;
        }
        val = (ss - m2 / cnt) / (cnt * 8.0f);
    }
#pragma unroll
    for (int off = 32; off > 0; off >>= 1) val += __shfl_down(val, off, 64);
    if (s == 0) out[0] = val;
}

extern "C" void kernel_launch(void* const* d_in, const int* in_sizes, int n_in,
                              void* d_out, int out_size, void* d_ws, size_t ws_size,
                              hipStream_t stream) {
    const float* variances = (const float*)d_in[0];  // [N, 8] fp32
    const int* labels = (const int*)d_in[1];         // [N] int32
    const int n = in_sizes[1];                       // N
    float* gacc = (float*)d_ws;                      // 640 floats of scratch

    hipMemsetAsync(d_ws, 0, NUM_INST * 10 * sizeof(float), stream);
    vsl_main<<<GRID, BLOCK, 0, stream>>>(variances, labels, gacc, n);
    vsl_final<<<1, 64, 0, stream>>>(gacc, (float*)d_out);
}